// Round 8
// baseline (235.051 us; speedup 1.0000x reference)
//
#include <hip/hip_runtime.h>
#include <math.h>

#define MTOT 9216
#define A_ 36
#define D0_ 64
#define EDGE_ 32
#define RBF_ 16
#define KNN 24
#define QIN_ 67    // D0 + KC
#define EPS_ 1e-5f

// ---- prep: state passthrough copy + pact build + xyz passthrough (fused) ----
__global__ void k_prep(const int* __restrict__ seq, const float* __restrict__ xyz,
                       const int* __restrict__ aamask,
                       const float4* __restrict__ state4, float4* __restrict__ out_state4,
                       float4* __restrict__ pact, float* __restrict__ out_xyz,
                       int* __restrict__ cnt) {
    int t = blockIdx.x * blockDim.x + threadIdx.x;
    if (t < MTOT * D0_ / 4) out_state4[t] = state4[t];
    if (t < MTOT) {
        int r = t / A_;
        int a = t - r * A_;
        int mk = (aamask[seq[r] * A_ + a] != 0);
        float x0 = xyz[t * 3 + 0], x1 = xyz[t * 3 + 1], x2 = xyz[t * 3 + 2];
        out_xyz[t * 3 + 0] = x0;
        out_xyz[t * 3 + 1] = x1;
        out_xyz[t * 3 + 2] = x2;
        if (mk) {
            int p = atomicAdd(cnt, 1);   // compiler wave-aggregates
            pact[p] = make_float4(x0, x1, x2, __int_as_float(t));
        }
    }
}

// ------- exact top-24, wave-per-atom, lane-parallel histogram (VALU-only),
// ------- mantissa-refined candidate filter + unrolled rank-select ----------
#define CAPN 256
#define WPB 2
#define UNR 4
#define CHUNK (64 * UNR)

__global__ __launch_bounds__(128) void k_nbr(const float4* __restrict__ pact,
                                             const int* __restrict__ cnt,
                                             int* __restrict__ idx) {
    __shared__ uint2 s_cand[WPB][CAPN];       // coarse-filtered candidates
    __shared__ uint2 s_cand2[WPB][CAPN + 4];  // refined candidates (+pad)

    const int nact = *cnt;
    const int lane = threadIdx.x & 63;
    const int wv = threadIdx.x >> 6;
    const int slot = blockIdx.x * WPB + wv;
    if (slot >= nact) return;            // wave-uniform exit; no block barriers

    const float4 pq = pact[slot];
    const int ia = __float_as_int(pq.w);
    const unsigned long long lmask = (1ULL << lane) - 1ULL;

    // prefetch helper: wave-uniform clamped base (chunk-0 dummy when OOB;
    // pact padded by 256 entries so all lanes stay in-bounds)
    auto pre = [&](float4* p, int base) {
        int b2 = (base < nact) ? base : 0;
        #pragma unroll
        for (int u = 0; u < UNR; ++u) p[u] = pact[b2 + u * 64 + lane];
    };

    // ---- pass A: cumulative histogram, 16 raw-bits thresholds (exp bins) ----
    unsigned cum[16];
    #pragma unroll
    for (int b = 0; b < 16; ++b) cum[b] = 0u;

    auto histo = [&](const float4* p, int base) {
        #pragma unroll
        for (int u = 0; u < UNR; ++u) {
            int c = base + u * 64 + lane;
            int j = __float_as_int(p[u].w);
            float dx = p[u].x - pq.x, dy = p[u].y - pq.y, dz = p[u].z - pq.z;
            float d2 = dx * dx + dy * dy + dz * dz;
            unsigned bt = (c < nact && j != ia) ? __float_as_uint(d2) : 0xFFFFFFFFu;
            #pragma unroll
            for (int b = 0; b < 16; ++b) {
                const unsigned L = (unsigned)(242 + 2 * b) << 22;   // == exp < 121+b
                cum[b] += (bt < L) ? 1u : 0u;
            }
        }
    };

    float4 pA[UNR], pB[UNR];
    pre(pA, 0);
    for (int base = 0; base < nact; base += 2 * CHUNK) {
        pre(pB, base + CHUNK);
        histo(pA, base);
        pre(pA, base + 2 * CHUNK);
        if (base + CHUNK < nact) histo(pB, base + CHUNK);
    }

    // wave-wide butterfly reduce; every lane ends with the full-wave totals
    #pragma unroll
    for (int b = 0; b < 16; ++b) {
        unsigned v = cum[b];
        #pragma unroll
        for (int off = 32; off > 0; off >>= 1)
            v += (unsigned)__shfl_xor((int)v, off, 64);
        cum[b] = v;
    }

    // ---- threshold of the 24th smallest (uniform across lanes) ----
    int bsel = 15;
    #pragma unroll
    for (int b = 15; b >= 0; --b) if (cum[b] >= KNN) bsel = b;
    const unsigned limit = (unsigned)(242 + 2 * bsel) << 22;

    // ---- pass B: ballot-compacted candidate collection (superset of top-24) ----
    int nsel = 0;
    auto collect = [&](const float4* p, int base) {
        #pragma unroll
        for (int u = 0; u < UNR; ++u) {
            int c = base + u * 64 + lane;
            int j = __float_as_int(p[u].w);
            float dx = p[u].x - pq.x, dy = p[u].y - pq.y, dz = p[u].z - pq.z;
            float d2 = dx * dx + dy * dy + dz * dz;
            unsigned bits = (c < nact && j != ia) ? __float_as_uint(d2) : 0xFFFFFFFFu;
            bool sel = bits < limit;
            unsigned long long m = __ballot(sel);
            int pos = nsel + (int)__popcll(m & lmask);
            if (sel && pos < CAPN) s_cand[wv][pos] = make_uint2(bits, (unsigned)j);
            nsel += (int)__popcll(m);
        }
    };

    pre(pA, 0);
    for (int base = 0; base < nact; base += 2 * CHUNK) {
        pre(pB, base + CHUNK);
        collect(pA, base);
        pre(pA, base + 2 * CHUNK);
        if (base + CHUNK < nact) collect(pB, base + CHUNK);
    }
    __builtin_amdgcn_wave_barrier();

    // ---- refinement: subdivide the selected coarse bin by top-4 mantissa ----
    const int n = min(nsel, CAPN);
    uint2 r0 = s_cand[wv][lane];
    uint2 r1 = s_cand[wv][lane + 64];
    uint2 r2 = s_cand[wv][lane + 128];
    uint2 r3 = s_cand[wv][lane + 192];
    const uint2 inval = make_uint2(0xFFFFFFFFu, 0xFFFFFFFFu);
    if (lane >= n)       r0 = inval;
    if (lane + 64 >= n)  r1 = inval;
    if (lane + 128 >= n) r2 = inval;
    if (lane + 192 >= n) r3 = inval;

    const unsigned prev = limit - (1u << 23);   // lower edge of selected bin
    unsigned c2r[16];
    #pragma unroll
    for (int m = 0; m < 16; ++m) {
        const unsigned T = prev + ((unsigned)(m + 1) << 19);
        unsigned s = (r0.x < T) ? 1u : 0u;
        s += (r1.x < T) ? 1u : 0u;
        s += (r2.x < T) ? 1u : 0u;
        s += (r3.x < T) ? 1u : 0u;
        c2r[m] = s;
    }
    #pragma unroll
    for (int m = 0; m < 16; ++m) {
        unsigned v = c2r[m];
        #pragma unroll
        for (int off = 32; off > 0; off >>= 1)
            v += (unsigned)__shfl_xor((int)v, off, 64);
        c2r[m] = v;
    }
    int msel = 15;
    #pragma unroll
    for (int m = 15; m >= 0; --m) if (c2r[m] >= KNN) msel = m;
    const unsigned limit2 = prev + ((unsigned)(msel + 1) << 19);
    // correctness: count(key < limit2) >= KNN; filtering by key < limit2
    // preserves exact global ranks of survivors.

    // ---- compact refined set ----
    int nsel2 = 0;
    {
        #pragma unroll
        for (int t = 0; t < 4; ++t) {
            uint2 r = (t == 0) ? r0 : (t == 1) ? r1 : (t == 2) ? r2 : r3;
            bool sel = r.x < limit2;
            unsigned long long m = __ballot(sel);
            int pos = nsel2 + (int)__popcll(m & lmask);
            if (sel && pos < CAPN) s_cand2[wv][pos] = r;
            nsel2 += (int)__popcll(m);
        }
    }
    __builtin_amdgcn_wave_barrier();

    const int n2 = min(nsel2, CAPN);
    if (lane < 4) s_cand2[wv][n2 + lane] = inval;   // x4 sentinel pad
    __builtin_amdgcn_wave_barrier();

    // ---- exact rank select, 4-wide unrolled ((d2, j) lex == lax.top_k) ----
    const int n2r = (n2 + 3) & ~3;
    for (int c = lane; c < n2; c += 64) {
        uint2 my = s_cand2[wv][c];
        int rank = 0;
        for (int c2 = 0; c2 < n2r; c2 += 4) {
            #pragma unroll
            for (int q = 0; q < 4; ++q) {
                uint2 o = s_cand2[wv][c2 + q];
                rank += (o.x < my.x || (o.x == my.x && o.y < my.y)) ? 1 : 0;
            }
        }
        if (rank < KNN) idx[ia * KNN + rank] = (int)my.y;
    }
}

// ---------------- per-atom attention -------------------------------------
// R4 body verbatim (separate LDS buffers — R7 unions regressed 63->71us) but
// 2 ATOMS PER BLOCK: 128 threads, wave wv owns atom slot blockIdx*2+wv.
// Rationale: residency was pinned at ~5.2 blocks/CU regardless of LDS
// (R4 19456 vs R7 15872 -> same 16% occupancy) -> workgroup DISPATCH RATE
// limited (~66 launches/us, 20us block lifetime). Halving launches doubles
// sustainable resident waves; LDS 2x19456=38912 -> 4 blocks x 2 waves =
// 8 waves/CU cap. Waves are independent (no __syncthreads anywhere).
#define WB() __builtin_amdgcn_wave_barrier()
#define APB 2   // atoms (waves) per block

#define s_kin   (sA_kin[wv])
#define s_qw    (sA_qw[wv])
#define s_wkin  (sA_wkin[wv])
#define s_dir   (sA_dir[wv])
#define s_rbf   (sA_rbf[wv])
#define s_l1j   (sA_l1j[wv])
#define s_qin   (sA_qin[wv])
#define s_q     (sA_q[wv])
#define s_logit (sA_logit[wv])
#define s_attn  (sA_attn[wv])
#define s_o0    (sA_o0[wv])
#define s_v1    (sA_v1[wv])
#define s_coef  (sA_coef[wv])
#define s_j     (sA_j[wv])
#define s_ok    (sA_ok[wv])
#define s_bc    (sA_bc[wv])
#define s_xi    (sA_xi[wv])

__global__ __launch_bounds__(128) void k_attn(
    const float* __restrict__ xyz, const int* __restrict__ seq,
    const int* __restrict__ num_bonds, const float* __restrict__ state,
    const float* __restrict__ grads,
    const float* __restrict__ We, const float* __restrict__ be,
    const float* __restrict__ Wq, const float* __restrict__ Wk,
    const float* __restrict__ Wv0, const float* __restrict__ Wv1,
    const float* __restrict__ Wo0, const float* __restrict__ Wself,
    const float* __restrict__ b0,
    const float4* __restrict__ pact, const int* __restrict__ cnt,
    const int* __restrict__ idxbuf,
    float* __restrict__ out_xyz, float* __restrict__ out_state) {
    const int nact = *cnt;
    const int lane = threadIdx.x & 63;
    const int wv = threadIdx.x >> 6;
    const int slot = blockIdx.x * APB + wv;
    if (slot >= nact) return;            // wave-uniform; no block barriers used
    const int i = __float_as_int(pact[slot].w);
    const int l15 = lane & 15;
    const int h = lane >> 4;

    __shared__ float sA_kin[APB][KNN][100];   // [node0(64) | e(32) | inv(3) | pad]
    __shared__ float sA_qw[APB][4][100];      // Wk folded with q, per head
    __shared__ float sA_wkin[APB][4][100];    // attn-weighted kin, per head
    __shared__ float sA_dir[APB][KNN][4];
    __shared__ float sA_rbf[APB][KNN][RBF_];
    __shared__ float sA_l1j[APB][KNN][3][3];
    __shared__ float sA_qin[APB][68];
    __shared__ float sA_q[APB][64];
    __shared__ float sA_logit[APB][4][KNN];
    __shared__ float sA_attn[APB][4][KNN];
    __shared__ float sA_o0[APB][64];
    __shared__ float sA_v1[APB][KNN][16];
    __shared__ float sA_coef[APB][KNN][4];
    __shared__ int   sA_j[APB][KNN];
    __shared__ int   sA_ok[APB][KNN];
    __shared__ int   sA_bc[APB][KNN];
    __shared__ float sA_xi[APB][3];

    // ---- P0: stage per-atom inputs ----
    s_qin[lane] = state[i * D0_ + lane];
    if (lane < 3) {
        float g0 = grads[(lane * MTOT + i) * 3 + 0];
        float g1 = grads[(lane * MTOT + i) * 3 + 1];
        float g2 = grads[(lane * MTOT + i) * 3 + 2];
        s_qin[D0_ + lane] = sqrtf(g0 * g0 + g1 * g1 + g2 * g2 + EPS_);
        s_xi[lane] = xyz[i * 3 + lane];
    }
    if (lane < KNN) {
        int j = idxbuf[i * KNN + lane];
        int ok = (j >= 0 && j < MTOT);
        int jj = ok ? j : 0;
        s_j[lane] = jj;
        s_ok[lane] = ok;
        float dx = xyz[jj * 3 + 0] - xyz[i * 3 + 0];
        float dy = xyz[jj * 3 + 1] - xyz[i * 3 + 1];
        float dz = xyz[jj * 3 + 2] - xyz[i * 3 + 2];
        float dist = sqrtf(dx * dx + dy * dy + dz * dz + EPS_);
        s_dir[lane][0] = dx / dist;
        s_dir[lane][1] = dy / dist;
        s_dir[lane][2] = dz / dist;
        s_dir[lane][3] = dist;
        int ri = i / A_, ai = i - ri * A_;
        int rj = jj / A_, aj = jj - rj * A_;
        int b = 0;
        if (rj == ri) b = num_bonds[(seq[ri] * A_ + ai) * A_ + aj];
        s_bc[lane] = min(max(b, 0), 4);
    }
    WB();

    // ---- P1: q projection (4-acc) ----
    {
        float q0 = 0.0f, q1 = 0.0f, q2 = 0.0f, q3 = 0.0f;
        for (int c = 0; c < 64; c += 4) {
            q0 += s_qin[c + 0] * Wq[(c + 0) * 64 + lane];
            q1 += s_qin[c + 1] * Wq[(c + 1) * 64 + lane];
            q2 += s_qin[c + 2] * Wq[(c + 2) * 64 + lane];
            q3 += s_qin[c + 3] * Wq[(c + 3) * 64 + lane];
        }
        q0 += s_qin[64] * Wq[64 * 64 + lane];
        q1 += s_qin[65] * Wq[65 * 64 + lane];
        q2 += s_qin[66] * Wq[66 * 64 + lane];
        s_q[lane] = (q0 + q1) + (q2 + q3);
    }
    // ---- P1: rbf ----
    for (int f = lane; f < KNN * RBF_; f += 64) {
        int k = f >> 4, r = f & 15;
        float mu = (6.0f / 15.0f) * (float)r;
        float d = s_dir[k][3] - mu;
        s_rbf[k][r] = expf(-d * d * 2.0f);
    }
    // ---- P1: neighbor node0 gather ----
    for (int k = 0; k < KNN; ++k) s_kin[k][lane] = state[s_j[k] * D0_ + lane];
    // ---- P1: l1 invariants + stash l1j ----
    for (int f = lane; f < KNN * 3; f += 64) {
        int k = f / 3, c = f - 3 * k;
        int jj = s_j[k];
        float g0 = grads[(c * MTOT + jj) * 3 + 0];
        float g1 = grads[(c * MTOT + jj) * 3 + 1];
        float g2 = grads[(c * MTOT + jj) * 3 + 2];
        s_l1j[k][c][0] = g0; s_l1j[k][c][1] = g1; s_l1j[k][c][2] = g2;
        s_kin[k][96 + c] = g0 * s_dir[k][0] + g1 * s_dir[k][1] + g2 * s_dir[k][2];
    }
    if (lane < KNN) s_kin[lane][99] = 0.0f;
    WB();

    // ---- P2: edge embedding -> kin[:, 64:96] (2-acc) ----
    for (int f = lane; f < KNN * EDGE_; f += 64) {
        int k = f >> 5, d = f & 31;
        float e0 = be[d] + We[(RBF_ + s_bc[k]) * EDGE_ + d];
        float e1 = 0.0f;
        #pragma unroll
        for (int r = 0; r < RBF_; r += 2) {
            e0 += s_rbf[k][r] * We[r * EDGE_ + d];
            e1 += s_rbf[k][r + 1] * We[(r + 1) * EDGE_ + d];
        }
        s_kin[k][64 + d] = e0 + e1;
    }
    // ---- P2: fold q into Wk: qW[h][c] = sum_d q[h,d] * Wk[c, h*16+d] ----
    for (int t = 0; t < 7; ++t) {
        int c = t * 16 + l15;
        if (c < 99) {
            const float* wk = &Wk[c * 64 + h * 16];
            float a0 = 0.0f, a1 = 0.0f;
            #pragma unroll
            for (int d = 0; d < 16; d += 2) {
                a0 += s_q[h * 16 + d] * wk[d];
                a1 += s_q[h * 16 + d + 1] * wk[d + 1];
            }
            s_qw[h][c] = a0 + a1;
        }
    }
    WB();

    // ---- P3: logits[h][k] = kin[k] . qW[h] (4-acc) ----
    for (int f = lane; f < 96; f += 64) {
        int k = f >> 2, hh = f & 3;
        const float4* k4 = (const float4*)s_kin[k];
        const float4* q4 = (const float4*)s_qw[hh];
        float a0 = 0.0f, a1 = 0.0f, a2 = 0.0f, a3 = 0.0f;
        #pragma unroll
        for (int c4 = 0; c4 < 24; c4 += 4) {
            float4 x0 = k4[c4 + 0], y0 = q4[c4 + 0];
            a0 += x0.x * y0.x + x0.y * y0.y + x0.z * y0.z + x0.w * y0.w;
            float4 x1 = k4[c4 + 1], y1 = q4[c4 + 1];
            a1 += x1.x * y1.x + x1.y * y1.y + x1.z * y1.z + x1.w * y1.w;
            float4 x2 = k4[c4 + 2], y2 = q4[c4 + 2];
            a2 += x2.x * y2.x + x2.y * y2.y + x2.z * y2.z + x2.w * y2.w;
            float4 x3 = k4[c4 + 3], y3 = q4[c4 + 3];
            a3 += x3.x * y3.x + x3.y * y3.y + x3.z * y3.z + x3.w * y3.w;
        }
        float acc = (a0 + a1) + (a2 + a3);
        acc += s_kin[k][96] * s_qw[hh][96] + s_kin[k][97] * s_qw[hh][97]
             + s_kin[k][98] * s_qw[hh][98];
        s_logit[hh][k] = s_ok[k] ? acc * 0.25f : -1e9f;
    }
    WB();

    // ---- P4a: softmax ----
    float attn[KNN];
    {
        float mx = -1e30f;
        #pragma unroll
        for (int k = 0; k < KNN; ++k) { attn[k] = s_logit[h][k]; mx = fmaxf(mx, attn[k]); }
        float s0 = 0.0f, s1 = 0.0f, s2 = 0.0f, s3 = 0.0f;
        #pragma unroll
        for (int k = 0; k < KNN; k += 4) {
            attn[k + 0] = expf(attn[k + 0] - mx); s0 += attn[k + 0];
            attn[k + 1] = expf(attn[k + 1] - mx); s1 += attn[k + 1];
            attn[k + 2] = expf(attn[k + 2] - mx); s2 += attn[k + 2];
            attn[k + 3] = expf(attn[k + 3] - mx); s3 += attn[k + 3];
        }
        float rs = 1.0f / ((s0 + s1) + (s2 + s3));
        #pragma unroll
        for (int k = 0; k < KNN; ++k) attn[k] *= rs;
    }
    s_attn[h][l15] = attn[l15];
    if (l15 < 8) s_attn[h][16 + l15] = attn[16 + l15];

    // ---- P4b: wkin[h][c] = sum_k attn[k] * kin[k][c] (4-acc) ----
    for (int t = 0; t < 7; ++t) {
        int c = t * 16 + l15;
        if (c < 99) {
            float a0 = 0.0f, a1 = 0.0f, a2 = 0.0f, a3 = 0.0f;
            #pragma unroll
            for (int k = 0; k < KNN; k += 4) {
                a0 += attn[k + 0] * s_kin[k + 0][c];
                a1 += attn[k + 1] * s_kin[k + 1][c];
                a2 += attn[k + 2] * s_kin[k + 2][c];
                a3 += attn[k + 3] * s_kin[k + 3][c];
            }
            s_wkin[h][c] = (a0 + a1) + (a2 + a3);
        }
    }
    // ---- P4b: v1[k][u] = kin[k] . Wv1[:,u] (4-acc) ----
    for (int t = 0; t < 6; ++t) {
        int k = (t * 64 + lane) >> 4;
        const float4* k4 = (const float4*)s_kin[k];
        const float* wv1p = &Wv1[l15];
        float a0 = 0.0f, a1 = 0.0f, a2 = 0.0f, a3 = 0.0f;
        #pragma unroll
        for (int c4 = 0; c4 < 24; c4 += 4) {
            float4 x0 = k4[c4 + 0];
            a0 += x0.x * wv1p[((c4 + 0) * 4 + 0) * 16] + x0.y * wv1p[((c4 + 0) * 4 + 1) * 16]
                + x0.z * wv1p[((c4 + 0) * 4 + 2) * 16] + x0.w * wv1p[((c4 + 0) * 4 + 3) * 16];
            float4 x1 = k4[c4 + 1];
            a1 += x1.x * wv1p[((c4 + 1) * 4 + 0) * 16] + x1.y * wv1p[((c4 + 1) * 4 + 1) * 16]
                + x1.z * wv1p[((c4 + 1) * 4 + 2) * 16] + x1.w * wv1p[((c4 + 1) * 4 + 3) * 16];
            float4 x2 = k4[c4 + 2];
            a2 += x2.x * wv1p[((c4 + 2) * 4 + 0) * 16] + x2.y * wv1p[((c4 + 2) * 4 + 1) * 16]
                + x2.z * wv1p[((c4 + 2) * 4 + 2) * 16] + x2.w * wv1p[((c4 + 2) * 4 + 3) * 16];
            float4 x3 = k4[c4 + 3];
            a3 += x3.x * wv1p[((c4 + 3) * 4 + 0) * 16] + x3.y * wv1p[((c4 + 3) * 4 + 1) * 16]
                + x3.z * wv1p[((c4 + 3) * 4 + 2) * 16] + x3.w * wv1p[((c4 + 3) * 4 + 3) * 16];
        }
        float acc = (a0 + a1) + (a2 + a3);
        acc += s_kin[k][96] * wv1p[96 * 16] + s_kin[k][97] * wv1p[97 * 16]
             + s_kin[k][98] * wv1p[98 * 16];
        s_v1[k][l15] = acc;
    }
    WB();

    // ---- P5: o0[lane] = sum_c wkin[h][c] * Wv0[c, lane] (4-acc) ----
    {
        float a0 = 0.0f, a1 = 0.0f, a2 = 0.0f, a3 = 0.0f;
        for (int c = 0; c < 96; c += 4) {
            a0 += s_wkin[h][c + 0] * Wv0[(c + 0) * 64 + lane];
            a1 += s_wkin[h][c + 1] * Wv0[(c + 1) * 64 + lane];
            a2 += s_wkin[h][c + 2] * Wv0[(c + 2) * 64 + lane];
            a3 += s_wkin[h][c + 3] * Wv0[(c + 3) * 64 + lane];
        }
        a0 += s_wkin[h][96] * Wv0[96 * 64 + lane];
        a1 += s_wkin[h][97] * Wv0[97 * 64 + lane];
        a2 += s_wkin[h][98] * Wv0[98 * 64 + lane];
        s_o0[lane] = (a0 + a1) + (a2 + a3);
    }
    WB();

    // ---- P6: out0 = o0 @ Wo0 + node0 @ Wself + b0 (4-acc) ----
    {
        float a0 = b0[lane], a1 = 0.0f, a2 = 0.0f, a3 = 0.0f;
        for (int t = 0; t < 64; t += 4) {
            a0 += s_o0[t + 0] * Wo0[(t + 0) * 64 + lane];
            a1 += s_o0[t + 1] * Wo0[(t + 1) * 64 + lane];
            a2 += s_o0[t + 2] * Wo0[(t + 2) * 64 + lane];
            a3 += s_o0[t + 3] * Wo0[(t + 3) * 64 + lane];
        }
        for (int t = 0; t < 64; t += 4) {
            a0 += s_qin[t + 0] * Wself[(t + 0) * 64 + lane];
            a1 += s_qin[t + 1] * Wself[(t + 1) * 64 + lane];
            a2 += s_qin[t + 2] * Wself[(t + 2) * 64 + lane];
            a3 += s_qin[t + 3] * Wself[(t + 3) * 64 + lane];
        }
        out_state[i * D0_ + lane] = (a0 + a1) + (a2 + a3);
    }
    // ---- P6b: coef[k][c] = sum_h attn[h][k] * v1[k][h*4+c] ----
    for (int f = lane; f < KNN * 4; f += 64) {
        int k = f >> 2, c = f & 3;
        float a2 = 0.0f;
        #pragma unroll
        for (int hh = 0; hh < 4; ++hh) a2 += s_attn[hh][k] * s_v1[k][hh * 4 + c];
        s_coef[k][c] = a2;
    }
    WB();

    // ---- P7: vector message -> xyz shift ----
    if (lane < 3) {
        float o1 = 0.0f;
        #pragma unroll
        for (int k = 0; k < KNN; ++k) {
            float t = s_coef[k][0] * s_dir[k][lane];
            t += s_coef[k][1] * s_l1j[k][0][lane];
            t += s_coef[k][2] * s_l1j[k][1][lane];
            t += s_coef[k][3] * s_l1j[k][2][lane];
            o1 += t;
        }
        out_xyz[i * 3 + lane] = s_xi[lane] + o1 / 100.0f;
    }
}

extern "C" void kernel_launch(void* const* d_in, const int* in_sizes, int n_in,
                              void* d_out, int out_size, void* d_ws, size_t ws_size,
                              hipStream_t stream) {
    const int*   seq    = (const int*)d_in[0];
    const float* xyz    = (const float*)d_in[1];
    const int*   aamask = (const int*)d_in[2];
    const int*   nbonds = (const int*)d_in[3];
    const float* state  = (const float*)d_in[4];
    const float* grads  = (const float*)d_in[5];
    const float* We    = (const float*)d_in[7];
    const float* be    = (const float*)d_in[8];
    const float* Wq    = (const float*)d_in[9];
    const float* Wk    = (const float*)d_in[10];
    const float* Wv0   = (const float*)d_in[11];
    const float* Wv1   = (const float*)d_in[12];
    const float* Wo0   = (const float*)d_in[13];
    const float* Wself = (const float*)d_in[14];
    const float* b0    = (const float*)d_in[15];

    float* out_xyz   = (float*)d_out;
    float* out_state = out_xyz + MTOT * 3;

    char* ws = (char*)d_ws;
    int*    cnt  = (int*)ws;                              // 16 B
    float4* pact = (float4*)(ws + 16);                    // (MTOT+256)*16 = 151552 B
    int*    idx  = (int*)(ws + 16 + 151552);              // 884736 B

    hipMemsetAsync(cnt, 0, 16, stream);
    k_prep<<<(MTOT * D0_ / 4 + 255) / 256, 256, 0, stream>>>(
        seq, xyz, aamask, (const float4*)state, (float4*)out_state,
        pact, out_xyz, cnt);
    k_nbr<<<(MTOT + WPB - 1) / WPB, WPB * 64, 0, stream>>>(pact, cnt, idx);
    k_attn<<<(MTOT + APB - 1) / APB, APB * 64, 0, stream>>>(
        xyz, seq, nbonds, state, grads, We, be, Wq, Wk,
        Wv0, Wv1, Wo0, Wself, b0, pact, cnt, idx,
        out_xyz, out_state);
}

// Round 9
// 199.480 us; speedup vs baseline: 1.1783x; 1.1783x over previous
//
#include <hip/hip_runtime.h>
#include <math.h>

#define MTOT 9216
#define A_ 36
#define D0_ 64
#define EDGE_ 32
#define RBF_ 16
#define KNN 24
#define QIN_ 67    // D0 + KC
#define EPS_ 1e-5f

// ---- prep: state passthrough copy + pact build + xyz passthrough (fused) ----
__global__ void k_prep(const int* __restrict__ seq, const float* __restrict__ xyz,
                       const int* __restrict__ aamask,
                       const float4* __restrict__ state4, float4* __restrict__ out_state4,
                       float4* __restrict__ pact, float* __restrict__ out_xyz,
                       int* __restrict__ cnt) {
    int t = blockIdx.x * blockDim.x + threadIdx.x;
    if (t < MTOT * D0_ / 4) out_state4[t] = state4[t];
    if (t < MTOT) {
        int r = t / A_;
        int a = t - r * A_;
        int mk = (aamask[seq[r] * A_ + a] != 0);
        float x0 = xyz[t * 3 + 0], x1 = xyz[t * 3 + 1], x2 = xyz[t * 3 + 2];
        out_xyz[t * 3 + 0] = x0;
        out_xyz[t * 3 + 1] = x1;
        out_xyz[t * 3 + 2] = x2;
        if (mk) {
            int p = atomicAdd(cnt, 1);   // compiler wave-aggregates
            pact[p] = make_float4(x0, x1, x2, __int_as_float(t));
        }
    }
}

// ------- exact top-24, wave-per-atom, lane-parallel histogram (VALU-only),
// ------- mantissa-refined candidate filter + unrolled rank-select ----------
#define CAPN 256
#define WPB 2
#define UNR 4
#define CHUNK (64 * UNR)

__global__ __launch_bounds__(128) void k_nbr(const float4* __restrict__ pact,
                                             const int* __restrict__ cnt,
                                             int* __restrict__ idx) {
    __shared__ uint2 s_cand[WPB][CAPN];       // coarse-filtered candidates
    __shared__ uint2 s_cand2[WPB][CAPN + 4];  // refined candidates (+pad)

    const int nact = *cnt;
    const int lane = threadIdx.x & 63;
    const int wv = threadIdx.x >> 6;
    const int slot = blockIdx.x * WPB + wv;
    if (slot >= nact) return;            // wave-uniform exit; no block barriers

    const float4 pq = pact[slot];
    const int ia = __float_as_int(pq.w);
    const unsigned long long lmask = (1ULL << lane) - 1ULL;

    auto pre = [&](float4* p, int base) {
        int b2 = (base < nact) ? base : 0;
        #pragma unroll
        for (int u = 0; u < UNR; ++u) p[u] = pact[b2 + u * 64 + lane];
    };

    // ---- pass A: cumulative histogram, 16 raw-bits thresholds (exp bins) ----
    unsigned cum[16];
    #pragma unroll
    for (int b = 0; b < 16; ++b) cum[b] = 0u;

    auto histo = [&](const float4* p, int base) {
        #pragma unroll
        for (int u = 0; u < UNR; ++u) {
            int c = base + u * 64 + lane;
            int j = __float_as_int(p[u].w);
            float dx = p[u].x - pq.x, dy = p[u].y - pq.y, dz = p[u].z - pq.z;
            float d2 = dx * dx + dy * dy + dz * dz;
            unsigned bt = (c < nact && j != ia) ? __float_as_uint(d2) : 0xFFFFFFFFu;
            #pragma unroll
            for (int b = 0; b < 16; ++b) {
                const unsigned L = (unsigned)(242 + 2 * b) << 22;   // == exp < 121+b
                cum[b] += (bt < L) ? 1u : 0u;
            }
        }
    };

    float4 pA[UNR], pB[UNR];
    pre(pA, 0);
    for (int base = 0; base < nact; base += 2 * CHUNK) {
        pre(pB, base + CHUNK);
        histo(pA, base);
        pre(pA, base + 2 * CHUNK);
        if (base + CHUNK < nact) histo(pB, base + CHUNK);
    }

    #pragma unroll
    for (int b = 0; b < 16; ++b) {
        unsigned v = cum[b];
        #pragma unroll
        for (int off = 32; off > 0; off >>= 1)
            v += (unsigned)__shfl_xor((int)v, off, 64);
        cum[b] = v;
    }

    int bsel = 15;
    #pragma unroll
    for (int b = 15; b >= 0; --b) if (cum[b] >= KNN) bsel = b;
    const unsigned limit = (unsigned)(242 + 2 * bsel) << 22;

    // ---- pass B: ballot-compacted candidate collection ----
    int nsel = 0;
    auto collect = [&](const float4* p, int base) {
        #pragma unroll
        for (int u = 0; u < UNR; ++u) {
            int c = base + u * 64 + lane;
            int j = __float_as_int(p[u].w);
            float dx = p[u].x - pq.x, dy = p[u].y - pq.y, dz = p[u].z - pq.z;
            float d2 = dx * dx + dy * dy + dz * dz;
            unsigned bits = (c < nact && j != ia) ? __float_as_uint(d2) : 0xFFFFFFFFu;
            bool sel = bits < limit;
            unsigned long long m = __ballot(sel);
            int pos = nsel + (int)__popcll(m & lmask);
            if (sel && pos < CAPN) s_cand[wv][pos] = make_uint2(bits, (unsigned)j);
            nsel += (int)__popcll(m);
        }
    };

    pre(pA, 0);
    for (int base = 0; base < nact; base += 2 * CHUNK) {
        pre(pB, base + CHUNK);
        collect(pA, base);
        pre(pA, base + 2 * CHUNK);
        if (base + CHUNK < nact) collect(pB, base + CHUNK);
    }
    __builtin_amdgcn_wave_barrier();

    // ---- refinement: subdivide the selected coarse bin by top-4 mantissa ----
    const int n = min(nsel, CAPN);
    uint2 r0 = s_cand[wv][lane];
    uint2 r1 = s_cand[wv][lane + 64];
    uint2 r2 = s_cand[wv][lane + 128];
    uint2 r3 = s_cand[wv][lane + 192];
    const uint2 inval = make_uint2(0xFFFFFFFFu, 0xFFFFFFFFu);
    if (lane >= n)       r0 = inval;
    if (lane + 64 >= n)  r1 = inval;
    if (lane + 128 >= n) r2 = inval;
    if (lane + 192 >= n) r3 = inval;

    const unsigned prev = limit - (1u << 23);   // lower edge of selected bin
    unsigned c2r[16];
    #pragma unroll
    for (int m = 0; m < 16; ++m) {
        const unsigned T = prev + ((unsigned)(m + 1) << 19);
        unsigned s = (r0.x < T) ? 1u : 0u;
        s += (r1.x < T) ? 1u : 0u;
        s += (r2.x < T) ? 1u : 0u;
        s += (r3.x < T) ? 1u : 0u;
        c2r[m] = s;
    }
    #pragma unroll
    for (int m = 0; m < 16; ++m) {
        unsigned v = c2r[m];
        #pragma unroll
        for (int off = 32; off > 0; off >>= 1)
            v += (unsigned)__shfl_xor((int)v, off, 64);
        c2r[m] = v;
    }
    int msel = 15;
    #pragma unroll
    for (int m = 15; m >= 0; --m) if (c2r[m] >= KNN) msel = m;
    const unsigned limit2 = prev + ((unsigned)(msel + 1) << 19);

    // ---- compact refined set ----
    int nsel2 = 0;
    {
        #pragma unroll
        for (int t = 0; t < 4; ++t) {
            uint2 r = (t == 0) ? r0 : (t == 1) ? r1 : (t == 2) ? r2 : r3;
            bool sel = r.x < limit2;
            unsigned long long m = __ballot(sel);
            int pos = nsel2 + (int)__popcll(m & lmask);
            if (sel && pos < CAPN) s_cand2[wv][pos] = r;
            nsel2 += (int)__popcll(m);
        }
    }
    __builtin_amdgcn_wave_barrier();

    const int n2 = min(nsel2, CAPN);
    if (lane < 4) s_cand2[wv][n2 + lane] = inval;   // x4 sentinel pad
    __builtin_amdgcn_wave_barrier();

    // ---- exact rank select, 4-wide unrolled ((d2, j) lex == lax.top_k) ----
    const int n2r = (n2 + 3) & ~3;
    for (int c = lane; c < n2; c += 64) {
        uint2 my = s_cand2[wv][c];
        int rank = 0;
        for (int c2 = 0; c2 < n2r; c2 += 4) {
            #pragma unroll
            for (int q = 0; q < 4; ++q) {
                uint2 o = s_cand2[wv][c2 + q];
                rank += (o.x < my.x || (o.x == my.x && o.y < my.y)) ? 1 : 0;
            }
        }
        if (rank < KNN) idx[ia * KNN + rank] = (int)my.y;
    }
}

// ---------------- per-atom attention -------------------------------------
// R4 structure exactly (1 atom/block, grid MTOT, separate LDS buffers,
// wave_barriers). Change this round: DS-instruction reduction. The wave's
// serial timeline carried ~8.5K cyc of LDS-pipe ops (m134 costs): scalar
// b32 broadcasts in every matvec + a 192-op P7 with 3/64 lanes active.
// All LDS reads vectorized to b128 (4x fewer instrs, 2x unit cost), v1 kin
// reads halved (2 u's/lane, 3 passes), gather via 16-lane float4 ds_write,
// P7 redesigned as 24-lane register compute + shfl_down tree (~5 DS ops).
#define WB() __builtin_amdgcn_wave_barrier()

__global__ __launch_bounds__(64, 2) void k_attn(
    const float* __restrict__ xyz, const int* __restrict__ seq,
    const int* __restrict__ num_bonds, const float* __restrict__ state,
    const float* __restrict__ grads,
    const float* __restrict__ We, const float* __restrict__ be,
    const float* __restrict__ Wq, const float* __restrict__ Wk,
    const float* __restrict__ Wv0, const float* __restrict__ Wv1,
    const float* __restrict__ Wo0, const float* __restrict__ Wself,
    const float* __restrict__ b0,
    const float4* __restrict__ pact, const int* __restrict__ cnt,
    const int* __restrict__ idxbuf,
    float* __restrict__ out_xyz, float* __restrict__ out_state) {
    const int nact = *cnt;
    if ((int)blockIdx.x >= nact) return;
    const int i = __float_as_int(pact[blockIdx.x].w);
    const int lane = threadIdx.x;
    const int l15 = lane & 15;
    const int h = lane >> 4;

    __shared__ __align__(16) float s_kin[KNN][100];   // [node0(64)|e(32)|inv(3)|pad]
    __shared__ __align__(16) float s_qw[4][100];      // Wk folded with q, per head
    __shared__ __align__(16) float s_wkin[4][100];    // attn-weighted kin, per head
    __shared__ __align__(16) float s_dir[KNN][4];
    __shared__ __align__(16) float s_rbf[KNN][RBF_];
    __shared__ __align__(16) float s_l1j[KNN][3][4];  // padded last dim for b128
    __shared__ __align__(16) float s_qin[68];
    __shared__ __align__(16) float s_q[64];
    __shared__ __align__(16) float s_logit[4][KNN];
    __shared__ __align__(16) float s_attn[4][KNN];
    __shared__ __align__(16) float s_o0[64];
    __shared__ __align__(16) float s_v1[KNN][16];
    __shared__ __align__(16) float s_coef[KNN][4];
    __shared__ int   s_j[KNN];
    __shared__ int   s_ok[KNN];
    __shared__ int   s_bc[KNN];
    __shared__ float s_xi[3];

    // ---- P0: stage per-atom inputs ----
    s_qin[lane] = state[i * D0_ + lane];
    if (lane < 3) {
        float g0 = grads[(lane * MTOT + i) * 3 + 0];
        float g1 = grads[(lane * MTOT + i) * 3 + 1];
        float g2 = grads[(lane * MTOT + i) * 3 + 2];
        s_qin[D0_ + lane] = sqrtf(g0 * g0 + g1 * g1 + g2 * g2 + EPS_);
        s_xi[lane] = xyz[i * 3 + lane];
    }
    if (lane < KNN) {
        int j = idxbuf[i * KNN + lane];
        int ok = (j >= 0 && j < MTOT);
        int jj = ok ? j : 0;
        s_j[lane] = jj;
        s_ok[lane] = ok;
        float dx = xyz[jj * 3 + 0] - xyz[i * 3 + 0];
        float dy = xyz[jj * 3 + 1] - xyz[i * 3 + 1];
        float dz = xyz[jj * 3 + 2] - xyz[i * 3 + 2];
        float dist = sqrtf(dx * dx + dy * dy + dz * dz + EPS_);
        *(float4*)&s_dir[lane][0] = make_float4(dx / dist, dy / dist, dz / dist, dist);
        int ri = i / A_, ai = i - ri * A_;
        int rj = jj / A_, aj = jj - rj * A_;
        int b = 0;
        if (rj == ri) b = num_bonds[(seq[ri] * A_ + ai) * A_ + aj];
        s_bc[lane] = min(max(b, 0), 4);
    }
    WB();

    // ---- P1: q projection (b128 broadcast reads) ----
    {
        float a0 = 0.0f, a1 = 0.0f, a2 = 0.0f, a3 = 0.0f;
        #pragma unroll
        for (int t4 = 0; t4 < 16; ++t4) {
            float4 qv = *(const float4*)&s_qin[t4 * 4];
            a0 += qv.x * Wq[(t4 * 4 + 0) * 64 + lane];
            a1 += qv.y * Wq[(t4 * 4 + 1) * 64 + lane];
            a2 += qv.z * Wq[(t4 * 4 + 2) * 64 + lane];
            a3 += qv.w * Wq[(t4 * 4 + 3) * 64 + lane];
        }
        a0 += s_qin[64] * Wq[64 * 64 + lane];
        a1 += s_qin[65] * Wq[65 * 64 + lane];
        a2 += s_qin[66] * Wq[66 * 64 + lane];
        s_q[lane] = (a0 + a1) + (a2 + a3);
    }
    // ---- P1: rbf ----
    for (int f = lane; f < KNN * RBF_; f += 64) {
        int k = f >> 4, r = f & 15;
        float mu = (6.0f / 15.0f) * (float)r;
        float d = s_dir[k][3] - mu;
        s_rbf[k][r] = expf(-d * d * 2.0f);
    }
    // ---- P1: neighbor node0 gather (16-lane float4, b128 ds_write) ----
    #pragma unroll
    for (int it = 0; it < 6; ++it) {
        int k = it * 4 + h;
        int jj = s_j[k];
        float4 sv = *(const float4*)&state[jj * D0_ + l15 * 4];
        *(float4*)&s_kin[k][l15 * 4] = sv;
    }
    // ---- P1: l1 invariants + stash l1j (padded rows) ----
    for (int f = lane; f < KNN * 3; f += 64) {
        int k = f / 3, c = f - 3 * k;
        int jj = s_j[k];
        float g0 = grads[(c * MTOT + jj) * 3 + 0];
        float g1 = grads[(c * MTOT + jj) * 3 + 1];
        float g2 = grads[(c * MTOT + jj) * 3 + 2];
        s_l1j[k][c][0] = g0; s_l1j[k][c][1] = g1; s_l1j[k][c][2] = g2;
        s_kin[k][96 + c] = g0 * s_dir[k][0] + g1 * s_dir[k][1] + g2 * s_dir[k][2];
    }
    if (lane < KNN) s_kin[lane][99] = 0.0f;   // zero pad (b128 tail reads)
    WB();

    // ---- P2: edge embedding -> kin[:, 64:96] (b128 rbf reads) ----
    for (int f = lane; f < KNN * EDGE_; f += 64) {
        int k = f >> 5, d = f & 31;
        float e0 = be[d] + We[(RBF_ + s_bc[k]) * EDGE_ + d];
        float e1 = 0.0f, e2 = 0.0f, e3 = 0.0f;
        #pragma unroll
        for (int r4 = 0; r4 < 4; ++r4) {
            float4 rv = *(const float4*)&s_rbf[k][r4 * 4];
            e0 += rv.x * We[(r4 * 4 + 0) * EDGE_ + d];
            e1 += rv.y * We[(r4 * 4 + 1) * EDGE_ + d];
            e2 += rv.z * We[(r4 * 4 + 2) * EDGE_ + d];
            e3 += rv.w * We[(r4 * 4 + 3) * EDGE_ + d];
        }
        s_kin[k][64 + d] = (e0 + e1) + (e2 + e3);
    }
    // ---- P2: fold q into Wk (b128 q reads) ----
    for (int t = 0; t < 7; ++t) {
        int c = t * 16 + l15;
        if (c < 99) {
            const float* wk = &Wk[c * 64 + h * 16];
            float a0 = 0.0f, a1 = 0.0f, a2 = 0.0f, a3 = 0.0f;
            #pragma unroll
            for (int d4 = 0; d4 < 4; ++d4) {
                float4 qv = *(const float4*)&s_q[h * 16 + d4 * 4];
                a0 += qv.x * wk[d4 * 4 + 0];
                a1 += qv.y * wk[d4 * 4 + 1];
                a2 += qv.z * wk[d4 * 4 + 2];
                a3 += qv.w * wk[d4 * 4 + 3];
            }
            s_qw[h][c] = (a0 + a1) + (a2 + a3);
        }
    }
    WB();

    // ---- P3: logits[h][k] = kin[k] . qW[h] (already b128) ----
    for (int f = lane; f < 96; f += 64) {
        int k = f >> 2, hh = f & 3;
        const float4* k4 = (const float4*)s_kin[k];
        const float4* q4 = (const float4*)s_qw[hh];
        float a0 = 0.0f, a1 = 0.0f, a2 = 0.0f, a3 = 0.0f;
        #pragma unroll
        for (int c4 = 0; c4 < 24; c4 += 4) {
            float4 x0 = k4[c4 + 0], y0 = q4[c4 + 0];
            a0 += x0.x * y0.x + x0.y * y0.y + x0.z * y0.z + x0.w * y0.w;
            float4 x1 = k4[c4 + 1], y1 = q4[c4 + 1];
            a1 += x1.x * y1.x + x1.y * y1.y + x1.z * y1.z + x1.w * y1.w;
            float4 x2 = k4[c4 + 2], y2 = q4[c4 + 2];
            a2 += x2.x * y2.x + x2.y * y2.y + x2.z * y2.z + x2.w * y2.w;
            float4 x3 = k4[c4 + 3], y3 = q4[c4 + 3];
            a3 += x3.x * y3.x + x3.y * y3.y + x3.z * y3.z + x3.w * y3.w;
        }
        float acc = (a0 + a1) + (a2 + a3);
        acc += s_kin[k][96] * s_qw[hh][96] + s_kin[k][97] * s_qw[hh][97]
             + s_kin[k][98] * s_qw[hh][98];
        s_logit[hh][k] = s_ok[k] ? acc * 0.25f : -1e9f;
    }
    WB();

    // ---- P4a: softmax (b128 logit loads) ----
    float attn[KNN];
    {
        float mx = -1e30f;
        #pragma unroll
        for (int k4 = 0; k4 < 6; ++k4) {
            float4 lg = *(const float4*)&s_logit[h][k4 * 4];
            attn[k4 * 4 + 0] = lg.x; attn[k4 * 4 + 1] = lg.y;
            attn[k4 * 4 + 2] = lg.z; attn[k4 * 4 + 3] = lg.w;
            mx = fmaxf(mx, fmaxf(fmaxf(lg.x, lg.y), fmaxf(lg.z, lg.w)));
        }
        float s0 = 0.0f, s1 = 0.0f, s2 = 0.0f, s3 = 0.0f;
        #pragma unroll
        for (int k = 0; k < KNN; k += 4) {
            attn[k + 0] = expf(attn[k + 0] - mx); s0 += attn[k + 0];
            attn[k + 1] = expf(attn[k + 1] - mx); s1 += attn[k + 1];
            attn[k + 2] = expf(attn[k + 2] - mx); s2 += attn[k + 2];
            attn[k + 3] = expf(attn[k + 3] - mx); s3 += attn[k + 3];
        }
        float rs = 1.0f / ((s0 + s1) + (s2 + s3));
        #pragma unroll
        for (int k = 0; k < KNN; ++k) attn[k] *= rs;
    }
    s_attn[h][l15] = attn[l15];
    if (l15 < 8) s_attn[h][16 + l15] = attn[16 + l15];

    // ---- P4b: wkin by c-quads (b128 kin reads/writes) ----
    #pragma unroll
    for (int t = 0; t < 2; ++t) {
        int q = t * 16 + l15;
        if (q < 25) {
            float ax = 0.0f, ay = 0.0f, az = 0.0f, aw = 0.0f;
            #pragma unroll
            for (int k = 0; k < KNN; ++k) {
                float4 kv = *(const float4*)&s_kin[k][q * 4];
                ax += attn[k] * kv.x; ay += attn[k] * kv.y;
                az += attn[k] * kv.z; aw += attn[k] * kv.w;
            }
            *(float4*)&s_wkin[h][q * 4] = make_float4(ax, ay, az, aw);
        }
    }
    // ---- P4b: v1[k][u] — 2 u's per lane, 3 passes (halved kin reads) ----
    #pragma unroll
    for (int t = 0; t < 3; ++t) {
        int k = t * 8 + (lane >> 3);
        int u = lane & 7;
        const float4* k4 = (const float4*)s_kin[k];
        const float* wv1p = &Wv1[u];
        float a0 = 0.0f, a1 = 0.0f, bA = 0.0f, bB = 0.0f;
        #pragma unroll
        for (int c4 = 0; c4 < 24; c4 += 2) {
            float4 x0 = k4[c4 + 0];
            a0 += x0.x * wv1p[((c4 + 0) * 4 + 0) * 16] + x0.y * wv1p[((c4 + 0) * 4 + 1) * 16]
                + x0.z * wv1p[((c4 + 0) * 4 + 2) * 16] + x0.w * wv1p[((c4 + 0) * 4 + 3) * 16];
            bA += x0.x * wv1p[((c4 + 0) * 4 + 0) * 16 + 8] + x0.y * wv1p[((c4 + 0) * 4 + 1) * 16 + 8]
                + x0.z * wv1p[((c4 + 0) * 4 + 2) * 16 + 8] + x0.w * wv1p[((c4 + 0) * 4 + 3) * 16 + 8];
            float4 x1 = k4[c4 + 1];
            a1 += x1.x * wv1p[((c4 + 1) * 4 + 0) * 16] + x1.y * wv1p[((c4 + 1) * 4 + 1) * 16]
                + x1.z * wv1p[((c4 + 1) * 4 + 2) * 16] + x1.w * wv1p[((c4 + 1) * 4 + 3) * 16];
            bB += x1.x * wv1p[((c4 + 1) * 4 + 0) * 16 + 8] + x1.y * wv1p[((c4 + 1) * 4 + 1) * 16 + 8]
                + x1.z * wv1p[((c4 + 1) * 4 + 2) * 16 + 8] + x1.w * wv1p[((c4 + 1) * 4 + 3) * 16 + 8];
        }
        float4 xt = k4[24];   // cols 96..99 (99 is zero pad)
        a0 += xt.x * wv1p[96 * 16] + xt.y * wv1p[97 * 16] + xt.z * wv1p[98 * 16];
        bA += xt.x * wv1p[96 * 16 + 8] + xt.y * wv1p[97 * 16 + 8] + xt.z * wv1p[98 * 16 + 8];
        s_v1[k][u] = a0 + a1;
        s_v1[k][u + 8] = bA + bB;
    }
    WB();

    // ---- P5: o0 = wkin[h] @ Wv0 (b128 wkin reads) ----
    {
        float a0 = 0.0f, a1 = 0.0f, a2 = 0.0f, a3 = 0.0f;
        #pragma unroll
        for (int q = 0; q < 24; ++q) {
            float4 wq = *(const float4*)&s_wkin[h][q * 4];
            a0 += wq.x * Wv0[(q * 4 + 0) * 64 + lane];
            a1 += wq.y * Wv0[(q * 4 + 1) * 64 + lane];
            a2 += wq.z * Wv0[(q * 4 + 2) * 64 + lane];
            a3 += wq.w * Wv0[(q * 4 + 3) * 64 + lane];
        }
        float4 wt = *(const float4*)&s_wkin[h][96];
        a0 += wt.x * Wv0[96 * 64 + lane];
        a1 += wt.y * Wv0[97 * 64 + lane];
        a2 += wt.z * Wv0[98 * 64 + lane];
        s_o0[lane] = (a0 + a1) + (a2 + a3);
    }
    WB();

    // ---- P6: out0 = o0 @ Wo0 + node0 @ Wself + b0 (b128 broadcasts) ----
    {
        float a0 = b0[lane], a1 = 0.0f, a2 = 0.0f, a3 = 0.0f;
        #pragma unroll
        for (int t4 = 0; t4 < 16; ++t4) {
            float4 ov = *(const float4*)&s_o0[t4 * 4];
            a0 += ov.x * Wo0[(t4 * 4 + 0) * 64 + lane];
            a1 += ov.y * Wo0[(t4 * 4 + 1) * 64 + lane];
            a2 += ov.z * Wo0[(t4 * 4 + 2) * 64 + lane];
            a3 += ov.w * Wo0[(t4 * 4 + 3) * 64 + lane];
        }
        #pragma unroll
        for (int t4 = 0; t4 < 16; ++t4) {
            float4 qv = *(const float4*)&s_qin[t4 * 4];
            a0 += qv.x * Wself[(t4 * 4 + 0) * 64 + lane];
            a1 += qv.y * Wself[(t4 * 4 + 1) * 64 + lane];
            a2 += qv.z * Wself[(t4 * 4 + 2) * 64 + lane];
            a3 += qv.w * Wself[(t4 * 4 + 3) * 64 + lane];
        }
        out_state[i * D0_ + lane] = (a0 + a1) + (a2 + a3);
    }
    // ---- P6b: coef[k][c] = sum_h attn[h][k] * v1[k][h*4+c] ----
    for (int f = lane; f < KNN * 4; f += 64) {
        int k = f >> 2, c = f & 3;
        float a2 = 0.0f;
        #pragma unroll
        for (int hh = 0; hh < 4; ++hh) a2 += s_attn[hh][k] * s_v1[k][hh * 4 + c];
        s_coef[k][c] = a2;
    }
    WB();

    // ---- P7: vector message -> xyz shift (24-lane compute + shfl tree) ----
    {
        float px = 0.0f, py = 0.0f, pz = 0.0f;
        if (lane < KNN) {
            float4 cf = *(const float4*)s_coef[lane];
            float4 dr = *(const float4*)&s_dir[lane][0];
            float4 l0 = *(const float4*)s_l1j[lane][0];
            float4 l1v = *(const float4*)s_l1j[lane][1];
            float4 l2 = *(const float4*)s_l1j[lane][2];
            px = cf.x * dr.x + cf.y * l0.x + cf.z * l1v.x + cf.w * l2.x;
            py = cf.x * dr.y + cf.y * l0.y + cf.z * l1v.y + cf.w * l2.y;
            pz = cf.x * dr.z + cf.y * l0.z + cf.z * l1v.z + cf.w * l2.z;
        }
        #pragma unroll
        for (int off = 16; off > 0; off >>= 1) {
            px += __shfl_down(px, off, 64);
            py += __shfl_down(py, off, 64);
            pz += __shfl_down(pz, off, 64);
        }
        if (lane == 0) {
            out_xyz[i * 3 + 0] = s_xi[0] + px / 100.0f;
            out_xyz[i * 3 + 1] = s_xi[1] + py / 100.0f;
            out_xyz[i * 3 + 2] = s_xi[2] + pz / 100.0f;
        }
    }
}

extern "C" void kernel_launch(void* const* d_in, const int* in_sizes, int n_in,
                              void* d_out, int out_size, void* d_ws, size_t ws_size,
                              hipStream_t stream) {
    const int*   seq    = (const int*)d_in[0];
    const float* xyz    = (const float*)d_in[1];
    const int*   aamask = (const int*)d_in[2];
    const int*   nbonds = (const int*)d_in[3];
    const float* state  = (const float*)d_in[4];
    const float* grads  = (const float*)d_in[5];
    const float* We    = (const float*)d_in[7];
    const float* be    = (const float*)d_in[8];
    const float* Wq    = (const float*)d_in[9];
    const float* Wk    = (const float*)d_in[10];
    const float* Wv0   = (const float*)d_in[11];
    const float* Wv1   = (const float*)d_in[12];
    const float* Wo0   = (const float*)d_in[13];
    const float* Wself = (const float*)d_in[14];
    const float* b0    = (const float*)d_in[15];

    float* out_xyz   = (float*)d_out;
    float* out_state = out_xyz + MTOT * 3;

    char* ws = (char*)d_ws;
    int*    cnt  = (int*)ws;                              // 16 B
    float4* pact = (float4*)(ws + 16);                    // (MTOT+256)*16 = 151552 B
    int*    idx  = (int*)(ws + 16 + 151552);              // 884736 B

    hipMemsetAsync(cnt, 0, 16, stream);
    k_prep<<<(MTOT * D0_ / 4 + 255) / 256, 256, 0, stream>>>(
        seq, xyz, aamask, (const float4*)state, (float4*)out_state,
        pact, out_xyz, cnt);
    k_nbr<<<(MTOT + WPB - 1) / WPB, WPB * 64, 0, stream>>>(pact, cnt, idx);
    k_attn<<<MTOT, 64, 0, stream>>>(xyz, seq, nbonds, state, grads, We, be, Wq, Wk,
                                    Wv0, Wv1, Wo0, Wself, b0, pact, cnt, idx,
                                    out_xyz, out_state);
}